// Round 7
// baseline (1557.124 us; speedup 1.0000x reference)
//
#include <hip/hip_runtime.h>
#include <hip/hip_bf16.h>

#define NN 100000
#define NE 1600000
#define NT 6250      // NN/16 node-tiles for MFMA

#define NBUCK  511       // ceil(NN/BRANGE)
#define BRANGE 196       // destination nodes per bucket (fits 8-bit local id)
#define CAPB   3584      // bucket capacity: mean 3136, sigma 56 -> 8-sigma margin
#define HPAD   65        // LDS row pitch (floats): +1 breaks bank alignment

#define BIN_EPB  2048    // edges per block-chunk in bin pass
#define BIN_CH   782     // ceil(NE/BIN_EPB)

typedef __attribute__((ext_vector_type(8))) short bf16x8;
typedef __attribute__((ext_vector_type(4))) float f32x4;

__device__ inline float2 bf16x2_unpack(unsigned v) {
    float2 r;
    r.x = __uint_as_float(v << 16);
    r.y = __uint_as_float(v & 0xffff0000u);
    return r;
}
__device__ inline unsigned bf16x2_pack(float a, float b) {
    __hip_bfloat162 h2(__float2bfloat16(a), __float2bfloat16(b));
    unsigned u;
    __builtin_memcpy(&u, &h2, 4);
    return u;
}

// ---- phase 1: bin edges by destination bucket, XCD-partitioned ----
// 511 append streams total (~64/XCD): each stream's current line stays dirty-
// resident in its XCD's L2 until full -> dense write-back (~6.4MB, not 66MB).
// Record: (dst_local<<24) | src  (dst_local<196 fits 8b, src<2^17 fits 24b).
__global__ __launch_bounds__(256) void bin_kernel(const int* __restrict__ rows,
                                                  const int* __restrict__ cols,
                                                  int* __restrict__ cur,
                                                  unsigned* __restrict__ eb) {
    int p     = blockIdx.x & 7;
    int chunk = blockIdx.x >> 3;
    int base  = chunk * BIN_EPB;
    #pragma unroll
    for (int i = 0; i < BIN_EPB / 256; i++) {
        int e = base + i * 256 + threadIdx.x;
        if (e < NE) {
            int c = __builtin_nontemporal_load(cols + e);
            int r = __builtin_nontemporal_load(rows + e);
            int bkt = (unsigned)c / BRANGE;
            if ((bkt & 7) == p) {
                int pos = atomicAdd(cur + bkt, 1);
                if (pos < CAPB)
                    eb[(size_t)bkt * CAPB + pos] =
                        ((unsigned)(c - bkt * BRANGE) << 24) | (unsigned)r;
            }
        }
    }
}

// ---- phase 2: per-node degree from bucket lists (LDS histogram) ----
__global__ __launch_bounds__(256) void deg2_kernel(const int* __restrict__ cur,
                                                   const unsigned* __restrict__ eb,
                                                   int* __restrict__ deg) {
    __shared__ int hist[BRANGE];
    int b = blockIdx.x;
    for (int t = threadIdx.x; t < BRANGE; t += 256) hist[t] = 0;
    __syncthreads();
    int cnt = min(cur[b], CAPB);
    const unsigned* seg = eb + (size_t)b * CAPB;
    for (int e = threadIdx.x; e < cnt; e += 256)
        atomicAdd(&hist[seg[e] >> 24], 1);
    __syncthreads();
    int lo = b * BRANGE;
    for (int t = threadIdx.x; t < BRANGE; t += 256) {
        int n = lo + t;
        if (n < NN) deg[n] = hist[t];
    }
}

// ---- xs = bf16(x * rsqrt(deg+1)) : prescaled source rows, 128B each ----
__global__ __launch_bounds__(256) void xscale_kernel(const float* __restrict__ x,
                                                     const int* __restrict__ deg,
                                                     unsigned* __restrict__ xs) {
    int i = blockIdx.x * 256 + threadIdx.x;           // NN*32 threads exactly
    int n = i >> 5;
    int d = (i & 31) * 2;
    float2 v = *(const float2*)(x + (size_t)n * 64 + d);
    float dv = rsqrtf((float)(deg[n] + 1));
    xs[i] = bf16x2_pack(v.x * dv, v.y * dv);
}

// ---- phase 3: per-bucket aggregation into LDS ----
// Block b owns 196 destination nodes; h accumulated fp32 in LDS (ds_add_f32).
// Half-wave per edge: broadcast 4B record, 1 random 128B xs row, 4 in flight.
// Epilogue: self-loop + dinv scale + bf16 pack, dense hbu write.
__global__ __launch_bounds__(256) void agg_kernel(const int* __restrict__ cur,
                                                  const unsigned* __restrict__ eb,
                                                  const unsigned* __restrict__ xs,
                                                  const int* __restrict__ deg,
                                                  unsigned* __restrict__ hbu) {
    __shared__ float h[BRANGE * HPAD];
    int b = blockIdx.x;
    for (int t = threadIdx.x; t < BRANGE * HPAD; t += 256) h[t] = 0.f;
    __syncthreads();

    int cnt = min(cur[b], CAPB);
    const unsigned* seg = eb + (size_t)b * CAPB;
    int hw = threadIdx.x >> 5;                        // half-wave 0..7
    int dp = threadIdx.x & 31;

    int e = hw;
    for (; e + 24 < cnt; e += 32) {                   // 4 rows in flight/half-wave
        unsigned u0 = seg[e];
        unsigned u1 = seg[e + 8];
        unsigned u2 = seg[e + 16];
        unsigned u3 = seg[e + 24];
        float2 v0 = bf16x2_unpack(xs[(size_t)(u0 & 0xFFFFFFu) * 32 + dp]);
        float2 v1 = bf16x2_unpack(xs[(size_t)(u1 & 0xFFFFFFu) * 32 + dp]);
        float2 v2 = bf16x2_unpack(xs[(size_t)(u2 & 0xFFFFFFu) * 32 + dp]);
        float2 v3 = bf16x2_unpack(xs[(size_t)(u3 & 0xFFFFFFu) * 32 + dp]);
        int a0 = (u0 >> 24) * HPAD + 2 * dp;
        int a1 = (u1 >> 24) * HPAD + 2 * dp;
        int a2 = (u2 >> 24) * HPAD + 2 * dp;
        int a3 = (u3 >> 24) * HPAD + 2 * dp;
        atomicAdd(&h[a0], v0.x); atomicAdd(&h[a0 + 1], v0.y);
        atomicAdd(&h[a1], v1.x); atomicAdd(&h[a1 + 1], v1.y);
        atomicAdd(&h[a2], v2.x); atomicAdd(&h[a2 + 1], v2.y);
        atomicAdd(&h[a3], v3.x); atomicAdd(&h[a3 + 1], v3.y);
    }
    for (; e < cnt; e += 8) {
        unsigned u = seg[e];
        float2 v = bf16x2_unpack(xs[(size_t)(u & 0xFFFFFFu) * 32 + dp]);
        int a = (u >> 24) * HPAD + 2 * dp;
        atomicAdd(&h[a], v.x); atomicAdd(&h[a + 1], v.y);
    }
    __syncthreads();

    int lo = b * BRANGE;
    for (int i = threadIdx.x; i < BRANGE * 32; i += 256) {
        int t = i >> 5, w = i & 31;
        int n = lo + t;
        if (n < NN) {
            float dn = rsqrtf((float)(deg[n] + 1));
            float2 sv = bf16x2_unpack(xs[(size_t)n * 32 + w]);
            float va = (h[t * HPAD + 2 * w]     + sv.x) * dn;
            float vb = (h[t * HPAD + 2 * w + 1] + sv.y) * dn;
            hbu[(size_t)n * 32 + w] = bf16x2_pack(va, vb);
        }
    }
}

// ---- pack Wcat[64 x 192] (3 experts side by side) into B-fragment order, bf16 ----
__global__ void wpack_kernel(const float* __restrict__ W, __hip_bfloat16* __restrict__ Bp) {
    int idx = blockIdx.x * 256 + threadIdx.x;         // 12288 total
    if (idx >= 12288) return;
    int j    = idx & 7;
    int lane = (idx >> 3) & 63;
    int rest = idx >> 9;                              // half*12 + t
    int t    = rest % 12;
    int kh   = rest / 12;
    int k    = kh * 32 + (lane >> 4) * 8 + j;
    int col  = t * 16 + (lane & 15);
    int i    = col >> 6;
    int d    = col & 63;
    Bp[idx] = __float2bfloat16(W[(i * 64 + k) * 64 + d]);
}

// ---- dense: [16-node tile] x [192 outs], K=64 bf16 MFMA; fused bias+relu+gate mix ----
__global__ __launch_bounds__(256) void mfma_kernel(const __hip_bfloat16* __restrict__ hb,
                                                   const short* __restrict__ Bp,
                                                   const float* __restrict__ b,
                                                   const float* __restrict__ gf,
                                                   const float* __restrict__ Wg,
                                                   float* __restrict__ out) {
    int wave = threadIdx.x >> 6;
    int lane = threadIdx.x & 63;
    int tile = blockIdx.x * 4 + wave;
    if (tile >= NT) return;
    int n0 = tile * 16;
    int m = lane & 15, quad = lane >> 4;

    const short* hrow = (const short*)hb + ((size_t)(n0 + m)) * 64 + quad * 8;
    bf16x8 a0 = *(const bf16x8*)(hrow);
    bf16x8 a1 = *(const bf16x8*)(hrow + 32);

    f32x4 acc[12];
    #pragma unroll
    for (int t = 0; t < 12; t++) acc[t] = (f32x4)(0.0f);

    #pragma unroll
    for (int kh = 0; kh < 2; kh++) {
        bf16x8 a = kh ? a1 : a0;
        #pragma unroll
        for (int t = 0; t < 12; t++) {
            bf16x8 bf = *(const bf16x8*)(Bp + ((size_t)((kh * 12 + t) * 64 + lane)) * 8);
            acc[t] = __builtin_amdgcn_mfma_f32_16x16x32_bf16(a, bf, acc[t], 0, 0, 0);
        }
    }

    float wg[12];
    #pragma unroll
    for (int k = 0; k < 12; k++) wg[k] = Wg[k];       // [GATE_C=4][EXPERTS=3] row-major

    #pragma unroll
    for (int reg = 0; reg < 4; reg++) {
        int n = n0 + quad * 4 + reg;
        float4 g = ((const float4*)gf)[n];
        float l0 = (g.x*wg[0] + g.y*wg[3] + g.z*wg[6] + g.w*wg[9])  * (1.0f/101.0f);
        float l1 = (g.x*wg[1] + g.y*wg[4] + g.z*wg[7] + g.w*wg[10]) * (1.0f/101.0f);
        float l2 = (g.x*wg[2] + g.y*wg[5] + g.z*wg[8] + g.w*wg[11]) * (1.0f/101.0f);
        float mx = fmaxf(l0, fmaxf(l1, l2));
        float e0 = __expf(l0 - mx), e1 = __expf(l1 - mx), e2 = __expf(l2 - mx);
        float inv = 1.0f / (e0 + e1 + e2);
        float g0 = e0 * inv, g1 = e1 * inv, g2 = e2 * inv;
        #pragma unroll
        for (int dpos = 0; dpos < 4; dpos++) {
            int d = dpos * 16 + m;
            float v0 = acc[0*4 + dpos][reg] + b[0*64 + d];
            float v1 = acc[1*4 + dpos][reg] + b[1*64 + d];
            float v2 = acc[2*4 + dpos][reg] + b[2*64 + d];
            float o = g0 * fmaxf(v0, 0.f) + g1 * fmaxf(v1, 0.f) + g2 * fmaxf(v2, 0.f);
            out[(size_t)n * 64 + d] = o;
        }
    }
}

extern "C" void kernel_launch(void* const* d_in, const int* in_sizes, int n_in,
                              void* d_out, int out_size, void* d_ws, size_t ws_size,
                              hipStream_t stream) {
    const float* x  = (const float*)d_in[0];
    const int*   ei = (const int*)d_in[1];
    const float* gf = (const float*)d_in[2];
    const float* W  = (const float*)d_in[3];
    const float* b  = (const float*)d_in[4];
    const float* Wg = (const float*)d_in[5];
    float* out = (float*)d_out;
    const int* rows = ei;        // edge_index[0] (sources)
    const int* cols = ei + NE;   // edge_index[1] (targets)

    char* ws = (char*)d_ws;
    size_t off = 0;
    auto alloc = [&](size_t bytes) {
        char* p = ws + off;
        off = (off + bytes + 255) & ~(size_t)255;
        return p;
    };
    int*            cur = (int*)alloc((size_t)NBUCK * 4);
    unsigned*       eb  = (unsigned*)alloc((size_t)NBUCK * CAPB * 4);
    int*            deg = (int*)alloc((size_t)NN * 4);
    unsigned*       xs  = (unsigned*)alloc((size_t)NN * 32 * 4);
    unsigned*       hbu = (unsigned*)alloc((size_t)NN * 32 * 4);
    __hip_bfloat16* Bp  = (__hip_bfloat16*)alloc(12288 * 2);

    hipMemsetAsync(cur, 0, (size_t)NBUCK * 4, stream);

    bin_kernel<<<8 * BIN_CH, 256, 0, stream>>>(rows, cols, cur, eb);
    deg2_kernel<<<NBUCK, 256, 0, stream>>>(cur, eb, deg);
    xscale_kernel<<<NN * 32 / 256, 256, 0, stream>>>(x, deg, xs);
    wpack_kernel<<<48, 256, 0, stream>>>(W, Bp);
    agg_kernel<<<NBUCK, 256, 0, stream>>>(cur, eb, xs, deg, hbu);
    mfma_kernel<<<(NT + 3) / 4, 256, 0, stream>>>((const __hip_bfloat16*)hbu,
                                                  (const short*)Bp, b, gf, Wg, out);
}

// Round 8
// 204.074 us; speedup vs baseline: 7.6302x; 7.6302x over previous
//
#include <hip/hip_runtime.h>
#include <hip/hip_bf16.h>

#define NN 100000
#define NE 1600000
#define NT 6250      // NN/16 node-tiles for MFMA

#define NBUCK  511       // buckets of BRANGE destination nodes
#define BRANGE 196       // fits 8-bit local id
#define CAPB   3584      // bucket capacity: mean 3136, sigma 56 -> 8-sigma margin
#define CHUNK  8192      // edges per bin block
#define NCH    196       // ceil(NE/CHUNK)

typedef __attribute__((ext_vector_type(8))) short bf16x8;
typedef __attribute__((ext_vector_type(4))) float f32x4;

__device__ inline float2 bf16x2_unpack(unsigned v) {
    float2 r;
    r.x = __uint_as_float(v << 16);
    r.y = __uint_as_float(v & 0xffff0000u);
    return r;
}
__device__ inline unsigned bf16x2_pack(float a, float b) {
    __hip_bfloat162 h2(__float2bfloat16(a), __float2bfloat16(b));
    unsigned u;
    __builtin_memcpy(&u, &h2, 4);
    return u;
}

// ---- phase 1: block-local counting sort by bucket + bulk-reserved dense runs ----
// One global atomicAdd per (block,bucket) reserves a whole run (~16 records), so
// per-counter contention is ~196 ops total and every global store lands in a
// dense, block-exclusive, wave-coalesced run.
__global__ __launch_bounds__(256) void bin_kernel(const int* __restrict__ rows,
                                                  const int* __restrict__ cols,
                                                  int* __restrict__ cur,
                                                  unsigned* __restrict__ eb) {
    __shared__ int hist[512];
    __shared__ int excl[512];
    __shared__ int lcur[512];
    __shared__ int gbase[512];
    __shared__ int s2[256];
    __shared__ unsigned staged[CHUNK];
    __shared__ unsigned short bktarr[CHUNK];
    int t = threadIdx.x;
    int base = blockIdx.x * CHUNK;
    int cnt = min(CHUNK, NE - base);

    hist[t] = 0; hist[t + 256] = 0;
    __syncthreads();
    #pragma unroll
    for (int k = 0; k < CHUNK / 256; k++) {
        int i = k * 256 + t;
        if (i < cnt) {
            int c = cols[base + i];
            atomicAdd(&hist[(unsigned)c / BRANGE], 1);
        }
    }
    __syncthreads();
    // exclusive scan of 512 entries via pair trick (256-thread Hillis-Steele)
    int a0 = hist[2 * t], a1 = hist[2 * t + 1];
    s2[t] = a0 + a1;
    __syncthreads();
    #pragma unroll
    for (int off = 1; off < 256; off <<= 1) {
        int v = (t >= off) ? s2[t - off] : 0;
        __syncthreads();
        s2[t] += v;
        __syncthreads();
    }
    int pe = (t > 0) ? s2[t - 1] : 0;
    excl[2 * t] = pe;      excl[2 * t + 1] = pe + a0;
    lcur[2 * t] = pe;      lcur[2 * t + 1] = pe + a0;
    gbase[2 * t]     = a0 ? atomicAdd(cur + 2 * t, a0) : 0;
    gbase[2 * t + 1] = a1 ? atomicAdd(cur + 2 * t + 1, a1) : 0;
    __syncthreads();
    // sort records into LDS
    #pragma unroll
    for (int k = 0; k < CHUNK / 256; k++) {
        int i = k * 256 + t;
        if (i < cnt) {
            int c = cols[base + i];
            int r = rows[base + i];
            int bkt = (unsigned)c / BRANGE;
            int lp = atomicAdd(&lcur[bkt], 1);
            staged[lp] = ((unsigned)(c - bkt * BRANGE) << 24) | (unsigned)r;
            bktarr[lp] = (unsigned short)bkt;
        }
    }
    __syncthreads();
    // flat coalesced copy-out: consecutive i in a run -> consecutive gpos
    #pragma unroll
    for (int k = 0; k < CHUNK / 256; k++) {
        int i = k * 256 + t;
        if (i < cnt) {
            int bkt = bktarr[i];
            int pos = gbase[bkt] + (i - excl[bkt]);
            if (pos < CAPB) eb[(size_t)bkt * CAPB + pos] = staged[i];
        }
    }
}

// ---- phase 2: sort each bucket's records by destination node; emit CSR ----
__global__ __launch_bounds__(256) void nodesort_kernel(const int* __restrict__ cur,
                                                       const unsigned* __restrict__ eb,
                                                       int* __restrict__ srcs2,
                                                       int* __restrict__ degg,
                                                       int* __restrict__ startg) {
    __shared__ int hist[256];
    __shared__ int sx[256];
    __shared__ int lcur[BRANGE];
    int b = blockIdx.x, t = threadIdx.x;
    hist[t] = 0;
    __syncthreads();
    int cnt = min(cur[b], CAPB);
    const unsigned* seg = eb + (size_t)b * CAPB;
    for (int e = t; e < cnt; e += 256) atomicAdd(&hist[seg[e] >> 24], 1);
    __syncthreads();
    int h = hist[t];
    sx[t] = h;
    __syncthreads();
    #pragma unroll
    for (int off = 1; off < 256; off <<= 1) {
        int v = (t >= off) ? sx[t - off] : 0;
        __syncthreads();
        sx[t] += v;
        __syncthreads();
    }
    int ex = (t > 0) ? sx[t - 1] : 0;
    if (t < BRANGE) {
        lcur[t] = ex;
        int n = b * BRANGE + t;
        if (n < NN) { degg[n] = h; startg[n] = ex; }
    }
    __syncthreads();
    for (int e = t; e < cnt; e += 256) {
        unsigned rec = seg[e];
        int dl = rec >> 24;
        int p = atomicAdd(&lcur[dl], 1);
        srcs2[(size_t)b * CAPB + p] = rec & 0xFFFFFFu;
    }
}

// ---- xs = bf16(x * rsqrt(deg+1)) : prescaled source rows, 128B each ----
__global__ __launch_bounds__(256) void xscale_kernel(const float* __restrict__ x,
                                                     const int* __restrict__ degg,
                                                     unsigned* __restrict__ xs) {
    int i = blockIdx.x * 256 + threadIdx.x;           // NN*32 threads exactly
    int n = i >> 5;
    int d = (i & 31) * 2;
    float2 v = *(const float2*)(x + (size_t)n * 64 + d);
    float dv = rsqrtf((float)(degg[n] + 1));
    xs[i] = bf16x2_pack(v.x * dv, v.y * dv);
}

// ---- phase 3: gather-aggregate from contiguous per-node runs ----
// wave = 1 node; halves (sub = lane>>5) stream alternating entries, 4 rows in
// flight per half.
__global__ __launch_bounds__(256) void gather_kernel(const int* __restrict__ srcs2,
                                                     const int* __restrict__ degg,
                                                     const int* __restrict__ startg,
                                                     const unsigned* __restrict__ xs,
                                                     unsigned* __restrict__ hbu) {
    int wave = threadIdx.x >> 6;
    int n = blockIdx.x * 4 + wave;                    // grid 25000 exact
    int lane = threadIdx.x & 63;
    int sub = lane >> 5;
    int dp = lane & 31;

    int deg = degg[n];
    int bkt = (unsigned)n / BRANGE;
    const int* seg = srcs2 + (size_t)bkt * CAPB + startg[n];

    float2 acc = make_float2(0.f, 0.f);
    int e = sub;
    for (; e + 6 < deg; e += 8) {                     // 4 rows in flight per half
        int r0 = seg[e];
        int r1 = seg[e + 2];
        int r2 = seg[e + 4];
        int r3 = seg[e + 6];
        float2 v0 = bf16x2_unpack(xs[(size_t)r0 * 32 + dp]);
        float2 v1 = bf16x2_unpack(xs[(size_t)r1 * 32 + dp]);
        float2 v2 = bf16x2_unpack(xs[(size_t)r2 * 32 + dp]);
        float2 v3 = bf16x2_unpack(xs[(size_t)r3 * 32 + dp]);
        acc.x += v0.x + v1.x + v2.x + v3.x;
        acc.y += v0.y + v1.y + v2.y + v3.y;
    }
    for (; e < deg; e += 2) {
        float2 v = bf16x2_unpack(xs[(size_t)seg[e] * 32 + dp]);
        acc.x += v.x;
        acc.y += v.y;
    }
    acc.x += __shfl_xor(acc.x, 32);
    acc.y += __shfl_xor(acc.y, 32);
    float2 sv = bf16x2_unpack(xs[(size_t)n * 32 + dp]);
    float dn = rsqrtf((float)(deg + 1));
    unsigned packed = bf16x2_pack((acc.x + sv.x) * dn, (acc.y + sv.y) * dn);
    if (sub == 0) hbu[(size_t)n * 32 + dp] = packed;
}

// ---- pack Wcat[64 x 192] (3 experts side by side) into B-fragment order, bf16 ----
__global__ void wpack_kernel(const float* __restrict__ W, __hip_bfloat16* __restrict__ Bp) {
    int idx = blockIdx.x * 256 + threadIdx.x;         // 12288 total
    if (idx >= 12288) return;
    int j    = idx & 7;
    int lane = (idx >> 3) & 63;
    int rest = idx >> 9;                              // half*12 + t
    int t    = rest % 12;
    int kh   = rest / 12;
    int k    = kh * 32 + (lane >> 4) * 8 + j;
    int col  = t * 16 + (lane & 15);
    int i    = col >> 6;
    int d    = col & 63;
    Bp[idx] = __float2bfloat16(W[(i * 64 + k) * 64 + d]);
}

// ---- dense: [16-node tile] x [192 outs], K=64 bf16 MFMA; fused bias+relu+gate mix ----
__global__ __launch_bounds__(256) void mfma_kernel(const __hip_bfloat16* __restrict__ hb,
                                                   const short* __restrict__ Bp,
                                                   const float* __restrict__ b,
                                                   const float* __restrict__ gf,
                                                   const float* __restrict__ Wg,
                                                   float* __restrict__ out) {
    int wave = threadIdx.x >> 6;
    int lane = threadIdx.x & 63;
    int tile = blockIdx.x * 4 + wave;
    if (tile >= NT) return;
    int n0 = tile * 16;
    int m = lane & 15, quad = lane >> 4;

    const short* hrow = (const short*)hb + ((size_t)(n0 + m)) * 64 + quad * 8;
    bf16x8 a0 = *(const bf16x8*)(hrow);
    bf16x8 a1 = *(const bf16x8*)(hrow + 32);

    f32x4 acc[12];
    #pragma unroll
    for (int t = 0; t < 12; t++) acc[t] = (f32x4)(0.0f);

    #pragma unroll
    for (int kh = 0; kh < 2; kh++) {
        bf16x8 a = kh ? a1 : a0;
        #pragma unroll
        for (int t = 0; t < 12; t++) {
            bf16x8 bf = *(const bf16x8*)(Bp + ((size_t)((kh * 12 + t) * 64 + lane)) * 8);
            acc[t] = __builtin_amdgcn_mfma_f32_16x16x32_bf16(a, bf, acc[t], 0, 0, 0);
        }
    }

    float wg[12];
    #pragma unroll
    for (int k = 0; k < 12; k++) wg[k] = Wg[k];       // [GATE_C=4][EXPERTS=3] row-major

    #pragma unroll
    for (int reg = 0; reg < 4; reg++) {
        int n = n0 + quad * 4 + reg;
        float4 g = ((const float4*)gf)[n];
        float l0 = (g.x*wg[0] + g.y*wg[3] + g.z*wg[6] + g.w*wg[9])  * (1.0f/101.0f);
        float l1 = (g.x*wg[1] + g.y*wg[4] + g.z*wg[7] + g.w*wg[10]) * (1.0f/101.0f);
        float l2 = (g.x*wg[2] + g.y*wg[5] + g.z*wg[8] + g.w*wg[11]) * (1.0f/101.0f);
        float mx = fmaxf(l0, fmaxf(l1, l2));
        float e0 = __expf(l0 - mx), e1 = __expf(l1 - mx), e2 = __expf(l2 - mx);
        float inv = 1.0f / (e0 + e1 + e2);
        float g0 = e0 * inv, g1 = e1 * inv, g2 = e2 * inv;
        #pragma unroll
        for (int dpos = 0; dpos < 4; dpos++) {
            int d = dpos * 16 + m;
            float v0 = acc[0*4 + dpos][reg] + b[0*64 + d];
            float v1 = acc[1*4 + dpos][reg] + b[1*64 + d];
            float v2 = acc[2*4 + dpos][reg] + b[2*64 + d];
            float o = g0 * fmaxf(v0, 0.f) + g1 * fmaxf(v1, 0.f) + g2 * fmaxf(v2, 0.f);
            out[(size_t)n * 64 + d] = o;
        }
    }
}

extern "C" void kernel_launch(void* const* d_in, const int* in_sizes, int n_in,
                              void* d_out, int out_size, void* d_ws, size_t ws_size,
                              hipStream_t stream) {
    const float* x  = (const float*)d_in[0];
    const int*   ei = (const int*)d_in[1];
    const float* gf = (const float*)d_in[2];
    const float* W  = (const float*)d_in[3];
    const float* b  = (const float*)d_in[4];
    const float* Wg = (const float*)d_in[5];
    float* out = (float*)d_out;
    const int* rows = ei;        // edge_index[0] (sources)
    const int* cols = ei + NE;   // edge_index[1] (targets)

    char* ws = (char*)d_ws;
    size_t off = 0;
    auto alloc = [&](size_t bytes) {
        char* p = ws + off;
        off = (off + bytes + 255) & ~(size_t)255;
        return p;
    };
    int*            cur    = (int*)alloc(512 * 4);
    unsigned*       eb     = (unsigned*)alloc((size_t)NBUCK * CAPB * 4);
    int*            srcs2  = (int*)alloc((size_t)NBUCK * CAPB * 4);
    int*            degg   = (int*)alloc((size_t)NN * 4);
    int*            startg = (int*)alloc((size_t)NN * 4);
    unsigned*       xs     = (unsigned*)alloc((size_t)NN * 32 * 4);
    unsigned*       hbu    = (unsigned*)alloc((size_t)NN * 32 * 4);
    __hip_bfloat16* Bp     = (__hip_bfloat16*)alloc(12288 * 2);

    hipMemsetAsync(cur, 0, 512 * 4, stream);

    bin_kernel<<<NCH, 256, 0, stream>>>(rows, cols, cur, eb);
    nodesort_kernel<<<NBUCK, 256, 0, stream>>>(cur, eb, srcs2, degg, startg);
    xscale_kernel<<<NN * 32 / 256, 256, 0, stream>>>(x, degg, xs);
    wpack_kernel<<<48, 256, 0, stream>>>(W, Bp);
    gather_kernel<<<NN / 4, 256, 0, stream>>>(srcs2, degg, startg, xs, hbu);
    mfma_kernel<<<(NT + 3) / 4, 256, 0, stream>>>((const __hip_bfloat16*)hbu,
                                                  (const short*)Bp, b, gf, Wg, out);
}